// Round 5
// baseline (2415.022 us; speedup 1.0000x reference)
//
#include <hip/hip_runtime.h>

typedef unsigned short u16;
typedef unsigned int u32;
typedef __attribute__((ext_vector_type(8))) short short8;
typedef __attribute__((ext_vector_type(4))) float floatx4;

#define EDIM 1024
#define H3   3072
#define HD   64
#define GEMM_LDS_BYTES 150528   // 64*1032 u16 (A) + 2*64*72 u16 (B dbuf)

__device__ __forceinline__ float bf2f(u16 u) {
    union { u32 i; float f; } x; x.i = ((u32)u) << 16; return x.f;
}
__device__ __forceinline__ u16 f2bf(float f) {
    u32 u = __float_as_uint(f);
    u32 r = u + 0x7fffu + ((u >> 16) & 1u);
    return (u16)(r >> 16);
}

// ---------------------------------------------------------------------------
// Detect input dtype (bf16 vs fp32) from bit patterns. flag=1 -> bf16.
// ---------------------------------------------------------------------------
__global__ void detect_dtype(const u16* __restrict__ t, int* __restrict__ flag)
{
    __shared__ int cnt;
    if (threadIdx.x == 0) cnt = 0;
    __syncthreads();
    u16 u = t[threadIdx.x * 2];
    int e = (u >> 7) & 0xFF;
    int ok = (u == 0) || (e >= 108 && e <= 136);
    atomicAdd(&cnt, ok);
    __syncthreads();
    if (threadIdx.x == 0) flag[0] = (cnt >= 128) ? 1 : 0;
}

// ---------------------------------------------------------------------------
// A-resident GEMM: C[M,N] = A[M,1024] @ W[N,1024]^T + bias[N], bf16 out.
// Block = 256 thr / 4 waves, owns 64 rows of A staged ONCE into padded LDS
// (64x1032 u16, +8 pad -> conflict-free b128 reads). Sweeps n-chunks of 64
// cols; B chunks (64x64) stream through padded double-buffered LDS with
// register prefetch, one barrier per K-step. K fixed at 1024.
// Wave w: rows (w>>1)*32.., cols (w&1)*32..; acc 2x2 floatx4.
// grid: (ceil(M/64), nsplit); each y handles nchunks chunks from y*nchunks.
// ---------------------------------------------------------------------------
__global__ __launch_bounds__(256) void gemm_ares(
    const void* __restrict__ Av, const void* __restrict__ Wv,
    const void* __restrict__ biasv, u16* __restrict__ C,
    int M, int N, int nchunks, int w_row0, int b_off,
    int a_from_input, const int* __restrict__ flag)
{
    extern __shared__ u16 lds[];
    u16* sA = lds;                 // [64][1032]
    u16* sB = lds + 64 * 1032;     // [2][64][72]
    const int K = 1024;
    const int is_bf = flag[0];
    const bool a_f32 = a_from_input && !is_bf;
    const bool w_f32 = !is_bf;
    const int tid = threadIdx.x, wave = tid >> 6, lane = tid & 63;
    const int m0 = blockIdx.x * 64;
    const int nc0 = blockIdx.y * nchunks;
    const int rg = wave >> 1, ch = wave & 1;
    const int r16 = lane & 15, q8 = (lane >> 4) * 8;
    const int brow = tid >> 3, bseg = (tid & 7) * 8;

    // ---- stage A slab (64 x 1024) into padded LDS, once ----
    if (!a_f32) {
        const u16* Ab = (const u16*)Av;
#pragma unroll
        for (int i = 0; i < 32; ++i) {
            int o = wave * 32 + i;
            int row = o >> 1, half = o & 1;
            int gr = m0 + row; if (gr > M - 1) gr = M - 1;
            const u16* gp = Ab + (size_t)gr * K + half * 512 + lane * 8;
            __builtin_amdgcn_global_load_lds(
                (const __attribute__((address_space(1))) void*)gp,
                (__attribute__((address_space(3))) void*)&sA[row * 1032 + half * 512],
                16, 0, 0);
        }
    } else {
        const float* Af = (const float*)Av;
        for (int i = 0; i < 32; ++i) {
            int idx = i * 256 + tid;          // 8192 segs of 8 u16
            int row = idx >> 7, seg = idx & 127;
            int gr = m0 + row; if (gr > M - 1) gr = M - 1;
            const float* ap = Af + (size_t)gr * K + seg * 8;
            float4 f0 = *(const float4*)ap, f1 = *(const float4*)(ap + 4);
            uint4 p;
            p.x = (u32)f2bf(f0.x) | ((u32)f2bf(f0.y) << 16);
            p.y = (u32)f2bf(f0.z) | ((u32)f2bf(f0.w) << 16);
            p.z = (u32)f2bf(f1.x) | ((u32)f2bf(f1.y) << 16);
            p.w = (u32)f2bf(f1.z) | ((u32)f2bf(f1.w) << 16);
            *(uint4*)&sA[row * 1032 + seg * 8] = p;
        }
    }

    // ---- B chunk register prefetch for it = 0 ----
    uint4 br0, br1;
    const int it_total = nchunks * 16;
    {
        int base_row = w_row0 + nc0 * 64;
        if (!w_f32) {
            const u16* Wb = (const u16*)Wv;
            br0 = *(const uint4*)(Wb + (size_t)(base_row + brow) * K + bseg);
            br1 = *(const uint4*)(Wb + (size_t)(base_row + 32 + brow) * K + bseg);
        } else {
            const float* Wf = (const float*)Wv;
            const float* p0 = Wf + (size_t)(base_row + brow) * K + bseg;
            const float* p1 = Wf + (size_t)(base_row + 32 + brow) * K + bseg;
            float4 a0 = *(const float4*)p0, a1 = *(const float4*)(p0 + 4);
            float4 b0 = *(const float4*)p1, b1 = *(const float4*)(p1 + 4);
            br0.x = (u32)f2bf(a0.x) | ((u32)f2bf(a0.y) << 16);
            br0.y = (u32)f2bf(a0.z) | ((u32)f2bf(a0.w) << 16);
            br0.z = (u32)f2bf(a1.x) | ((u32)f2bf(a1.y) << 16);
            br0.w = (u32)f2bf(a1.z) | ((u32)f2bf(a1.w) << 16);
            br1.x = (u32)f2bf(b0.x) | ((u32)f2bf(b0.y) << 16);
            br1.y = (u32)f2bf(b0.z) | ((u32)f2bf(b0.w) << 16);
            br1.z = (u32)f2bf(b1.x) | ((u32)f2bf(b1.y) << 16);
            br1.w = (u32)f2bf(b1.z) | ((u32)f2bf(b1.w) << 16);
        }
    }

    floatx4 acc[2][2];
#pragma unroll
    for (int i = 0; i < 2; ++i)
#pragma unroll
        for (int j = 0; j < 2; ++j)
            acc[i][j] = (floatx4){0.f, 0.f, 0.f, 0.f};

    for (int it = 0; it < it_total; ++it) {
        const int k0 = (it & 15) << 6;
        u16* bb = sB + (it & 1) * 4608;
        // publish staged B regs into LDS (buffer it&1; other buffer may still
        // be read by slower waves from the previous iteration)
        *(uint4*)&bb[brow * 72 + bseg] = br0;
        *(uint4*)&bb[(32 + brow) * 72 + bseg] = br1;
        // prefetch next chunk's B into registers (in flight across barrier+compute)
        if (it + 1 < it_total) {
            int itn = it + 1;
            int base_row = w_row0 + (nc0 + (itn >> 4)) * 64;
            int kn = (itn & 15) << 6;
            if (!w_f32) {
                const u16* Wb = (const u16*)Wv;
                br0 = *(const uint4*)(Wb + (size_t)(base_row + brow) * K + kn + bseg);
                br1 = *(const uint4*)(Wb + (size_t)(base_row + 32 + brow) * K + kn + bseg);
            } else {
                const float* Wf = (const float*)Wv;
                const float* p0 = Wf + (size_t)(base_row + brow) * K + kn + bseg;
                const float* p1 = Wf + (size_t)(base_row + 32 + brow) * K + kn + bseg;
                float4 a0 = *(const float4*)p0, a1 = *(const float4*)(p0 + 4);
                float4 b0 = *(const float4*)p1, b1 = *(const float4*)(p1 + 4);
                br0.x = (u32)f2bf(a0.x) | ((u32)f2bf(a0.y) << 16);
                br0.y = (u32)f2bf(a0.z) | ((u32)f2bf(a0.w) << 16);
                br0.z = (u32)f2bf(a1.x) | ((u32)f2bf(a1.y) << 16);
                br0.w = (u32)f2bf(a1.z) | ((u32)f2bf(a1.w) << 16);
                br1.x = (u32)f2bf(b0.x) | ((u32)f2bf(b0.y) << 16);
                br1.y = (u32)f2bf(b0.z) | ((u32)f2bf(b0.w) << 16);
                br1.z = (u32)f2bf(b1.x) | ((u32)f2bf(b1.y) << 16);
                br1.w = (u32)f2bf(b1.z) | ((u32)f2bf(b1.w) << 16);
            }
        }
        __syncthreads();
        // ---- compute this K-step ----
#pragma unroll
        for (int kk = 0; kk < 2; ++kk) {
            short8 af[2], bg[2];
#pragma unroll
            for (int i = 0; i < 2; ++i)
                af[i] = *(const short8*)&sA[(rg * 32 + 16 * i + r16) * 1032 + k0 + kk * 32 + q8];
#pragma unroll
            for (int j = 0; j < 2; ++j)
                bg[j] = *(const short8*)&bb[(ch * 32 + 16 * j + r16) * 72 + kk * 32 + q8];
#pragma unroll
            for (int i = 0; i < 2; ++i)
#pragma unroll
                for (int j = 0; j < 2; ++j)
                    acc[i][j] = __builtin_amdgcn_mfma_f32_16x16x32_bf16(
                        af[i], bg[j], acc[i][j], 0, 0, 0);
        }
        // ---- chunk finished: epilogue + reset acc ----
        if ((it & 15) == 15) {
            int nc = nc0 + (it >> 4);
#pragma unroll
            for (int j = 0; j < 2; ++j) {
                int col = nc * 64 + ch * 32 + 16 * j + r16;
                float bv = w_f32 ? ((const float*)biasv)[b_off + col]
                                 : bf2f(((const u16*)biasv)[b_off + col]);
#pragma unroll
                for (int i = 0; i < 2; ++i) {
                    int rowb = m0 + rg * 32 + 16 * i + (lane >> 4) * 4;
#pragma unroll
                    for (int r = 0; r < 4; ++r) {
                        int row = rowb + r;
                        if (row < M)
                            C[(size_t)row * N + col] = f2bf(acc[i][j][r] + bv);
                    }
                    acc[i][j] = (floatx4){0.f, 0.f, 0.f, 0.f};
                }
            }
        }
    }
}

// ---------------------------------------------------------------------------
// MFMA flash attention (unchanged — passing).
// ---------------------------------------------------------------------------
__global__ __launch_bounds__(256) void attn_flash(
    const u16* __restrict__ qkv, u16* __restrict__ out, int L, int causal)
{
    __shared__ u16 sK[64 * 64];
    __shared__ u16 sVt[64 * 64];
    __shared__ u16 sP[4 * 16 * 64];
    const int tid = threadIdx.x;
    const int wave = tid >> 6, lane = tid & 63;
    const int h = blockIdx.y, g = blockIdx.z, qt = blockIdx.x;
    const size_t grow0 = (size_t)g * L;
    const int qw0 = qt * 64 + wave * 16;
    const int r16 = lane & 15, q8 = (lane >> 4) * 8;

    short8 qf0, qf1;
    {
        const u16* qp = qkv + (grow0 + qw0 + r16) * (size_t)H3 + h * HD + q8;
        qf0 = *(const short8*)qp;
        qf1 = *(const short8*)(qp + 32);
    }

    floatx4 o_acc[4];
#pragma unroll
    for (int dg = 0; dg < 4; ++dg) o_acc[dg] = (floatx4){0.f, 0.f, 0.f, 0.f};
    float m_r[4], l_r[4];
#pragma unroll
    for (int r = 0; r < 4; ++r) { m_r[r] = -3.0e38f; l_r[r] = 0.f; }

    u16* sPw = sP + wave * 1024;
    const int nch = causal ? (qt + 1) : (L >> 6);

    for (int c = 0; c < nch; ++c) {
        const int k0 = c * 64;
        __syncthreads();
#pragma unroll
        for (int t = 0; t < 2; ++t) {
            int idx = t * 256 + tid;
            int r = idx >> 3, c8 = (idx & 7) * 8;
            const u16* kp = qkv + (grow0 + k0 + r) * (size_t)H3 + EDIM + h * HD + c8;
            *(uint4*)&sK[r * 64 + c8] = *(const uint4*)kp;
            uint4 vw = *(const uint4*)(kp + EDIM);
            u32 vu[4] = {vw.x, vw.y, vw.z, vw.w};
#pragma unroll
            for (int i = 0; i < 4; ++i) {
                sVt[(c8 + 2 * i) * 64 + r]     = (u16)(vu[i] & 0xffffu);
                sVt[(c8 + 2 * i + 1) * 64 + r] = (u16)(vu[i] >> 16);
            }
        }
        __syncthreads();

        float sc[4][4];
#pragma unroll
        for (int kg = 0; kg < 4; ++kg) {
            const u16* kb = &sK[(kg * 16 + r16) * 64];
            short8 kf0 = *(const short8*)(kb + q8);
            short8 kf1 = *(const short8*)(kb + 32 + q8);
            floatx4 a = (floatx4){0.f, 0.f, 0.f, 0.f};
            a = __builtin_amdgcn_mfma_f32_16x16x32_bf16(qf0, kf0, a, 0, 0, 0);
            a = __builtin_amdgcn_mfma_f32_16x16x32_bf16(qf1, kf1, a, 0, 0, 0);
#pragma unroll
            for (int r = 0; r < 4; ++r) sc[kg][r] = a[r] * 0.125f;
        }
        const bool domask = causal && (k0 + 63 > qw0);
        if (domask) {
#pragma unroll
            for (int kg = 0; kg < 4; ++kg)
#pragma unroll
                for (int r = 0; r < 4; ++r) {
                    int key = k0 + kg * 16 + r16;
                    int qg  = qw0 + (lane >> 4) * 4 + r;
                    if (key > qg) sc[kg][r] = -3.0e38f;
                }
        }
        float rmax[4];
#pragma unroll
        for (int r = 0; r < 4; ++r)
            rmax[r] = fmaxf(fmaxf(sc[0][r], sc[1][r]), fmaxf(sc[2][r], sc[3][r]));
#pragma unroll
        for (int m = 1; m <= 8; m <<= 1)
#pragma unroll
            for (int r = 0; r < 4; ++r)
                rmax[r] = fmaxf(rmax[r], __shfl_xor(rmax[r], m));
        float alpha[4], rsum[4];
#pragma unroll
        for (int r = 0; r < 4; ++r) {
            float mn = fmaxf(m_r[r], rmax[r]);
            alpha[r] = __expf(m_r[r] - mn);
            m_r[r] = mn; rsum[r] = 0.f;
        }
#pragma unroll
        for (int kg = 0; kg < 4; ++kg)
#pragma unroll
            for (int r = 0; r < 4; ++r) {
                float p = __expf(sc[kg][r] - m_r[r]);
                rsum[r] += p;
                sPw[((lane >> 4) * 4 + r) * 64 + kg * 16 + r16] = f2bf(p);
            }
#pragma unroll
        for (int m = 1; m <= 8; m <<= 1)
#pragma unroll
            for (int r = 0; r < 4; ++r)
                rsum[r] += __shfl_xor(rsum[r], m);
#pragma unroll
        for (int r = 0; r < 4; ++r) l_r[r] = l_r[r] * alpha[r] + rsum[r];
#pragma unroll
        for (int dg = 0; dg < 4; ++dg)
#pragma unroll
            for (int r = 0; r < 4; ++r) o_acc[dg][r] *= alpha[r];

        __asm__ volatile("" ::: "memory");

#pragma unroll
        for (int kc = 0; kc < 2; ++kc) {
            short8 pf = *(const short8*)&sPw[r16 * 64 + kc * 32 + q8];
#pragma unroll
            for (int dg = 0; dg < 4; ++dg) {
                short8 vf = *(const short8*)&sVt[(dg * 16 + r16) * 64 + kc * 32 + q8];
                o_acc[dg] = __builtin_amdgcn_mfma_f32_16x16x32_bf16(pf, vf, o_acc[dg], 0, 0, 0);
            }
        }
    }

    float inv[4];
#pragma unroll
    for (int r = 0; r < 4; ++r) inv[r] = 1.f / l_r[r];
#pragma unroll
    for (int dg = 0; dg < 4; ++dg)
#pragma unroll
        for (int r = 0; r < 4; ++r) {
            int q = qw0 + (lane >> 4) * 4 + r;
            out[(grow0 + q) * (size_t)EDIM + h * HD + dg * 16 + r16] =
                f2bf(o_acc[dg][r] * inv[r]);
        }
}

// ---------------------------------------------------------------------------
// Single-query cross attention. One wave per (head, group).
// ---------------------------------------------------------------------------
__global__ __launch_bounds__(64) void attn_cross(
    const u16* __restrict__ kv, const u16* __restrict__ qv,
    u16* __restrict__ out, int mode)
{
    const int h = blockIdx.x, gi = blockIdx.y, lane = threadIdx.x;
    int Lk, kvStride, kOff, vOff, qRow;
    size_t kvRow0;
    if (mode == 0) {
        Lk = 256; kvStride = H3; kOff = EDIM; vOff = 2 * EDIM;
        kvRow0 = (size_t)gi * 256;
        int s = gi >> 2, b = gi & 3;
        qRow = b * 16 + s;
    } else {
        Lk = 1040; kvStride = 2 * EDIM; kOff = 0; vOff = EDIM;
        kvRow0 = (size_t)gi * 1040;
        qRow = gi;
    }
    __shared__ float sq[64];
    __shared__ float sp[1040];
    sq[lane] = bf2f(qv[(size_t)qRow * EDIM + h * HD + lane]);
    __syncthreads();

    const int nt = (Lk + 63) >> 6;
    float mloc = -3.0e38f;
    for (int t = 0; t < nt; ++t) {
        int j = t * 64 + lane;
        if (j < Lk) {
            const uint4* kp = (const uint4*)(kv + (kvRow0 + j) * (size_t)kvStride + kOff + h * HD);
            float a0 = 0, a1 = 0;
#pragma unroll
            for (int tt = 0; tt < 8; ++tt) {
                uint4 w = kp[tt];
                u32 u[4] = {w.x, w.y, w.z, w.w};
#pragma unroll
                for (int i = 0; i < 4; ++i) {
                    a0 += sq[tt * 8 + i * 2]     * bf2f((u16)(u[i] & 0xffffu));
                    a1 += sq[tt * 8 + i * 2 + 1] * bf2f((u16)(u[i] >> 16));
                }
            }
            float s_ = (a0 + a1) * 0.125f;
            sp[j] = s_;
            mloc = fmaxf(mloc, s_);
        }
    }
#pragma unroll
    for (int off = 32; off; off >>= 1) mloc = fmaxf(mloc, __shfl_xor(mloc, off));
    float lsum = 0.f;
    for (int t = 0; t < nt; ++t) {
        int j = t * 64 + lane;
        if (j < Lk) { float p = __expf(sp[j] - mloc); sp[j] = p; lsum += p; }
    }
#pragma unroll
    for (int off = 32; off; off >>= 1) lsum += __shfl_xor(lsum, off);
    __syncthreads();

    float o = 0.f;
    for (int j = 0; j < Lk; ++j)
        o += sp[j] * bf2f(kv[(kvRow0 + j) * (size_t)kvStride + vOff + h * HD + lane]);
    out[(size_t)qRow * EDIM + h * HD + lane] = f2bf(o / lsum);
}

// ---------------------------------------------------------------------------
__global__ __launch_bounds__(256) void build_ctx(
    const u16* __restrict__ to, const u16* __restrict__ co, u16* __restrict__ ctx)
{
    int idx = blockIdx.x * 256 + threadIdx.x;
    int row = idx >> 7, c8 = (idx & 127) << 3;
    int b = row / 1040, t = row - b * 1040;
    const u16* src = (t < 1024)
        ? (to + ((size_t)(b * 1024 + t) * EDIM + c8))
        : (co + ((size_t)(b * 16 + (t - 1024)) * EDIM + c8));
    *(uint4*)(ctx + (size_t)row * EDIM + c8) = *(const uint4*)src;
}

// ---------------------------------------------------------------------------
__global__ __launch_bounds__(256) void emit_out(
    const u16* __restrict__ src, void* __restrict__ dst, int n8,
    const int* __restrict__ flag)
{
    int idx = blockIdx.x * 256 + threadIdx.x;
    if (idx >= n8) return;
    const u16* s = src + (size_t)idx * 8;
    if (flag[0]) {
        *(uint4*)((u16*)dst + (size_t)idx * 8) = *(const uint4*)s;
    } else {
        float4 f0, f1;
        f0.x = bf2f(s[0]); f0.y = bf2f(s[1]); f0.z = bf2f(s[2]); f0.w = bf2f(s[3]);
        f1.x = bf2f(s[4]); f1.y = bf2f(s[5]); f1.z = bf2f(s[6]); f1.w = bf2f(s[7]);
        float4* dp = (float4*)dst + (size_t)idx * 2;
        dp[0] = f0; dp[1] = f1;
    }
}

// ---------------------------------------------------------------------------
extern "C" void kernel_launch(void* const* d_in, const int* in_sizes, int n_in,
                              void* d_out, int out_size, void* d_ws, size_t ws_size,
                              hipStream_t stream)
{
    const void* text  = d_in[0];
    const void* patch = d_in[1];
    const void* cls   = d_in[2];
    const void* intok = d_in[3];
    const void* t_win  = d_in[4];  const void* t_bin  = d_in[5];
    const void* t_wout = d_in[6];  const void* t_bout = d_in[7];
    const void* p_win  = d_in[8];  const void* p_bin  = d_in[9];
    const void* p_wout = d_in[10]; const void* p_bout = d_in[11];
    const void* i_win  = d_in[12]; const void* i_bin  = d_in[13];
    const void* i_wout = d_in[14]; const void* i_bout = d_in[15];

    u16* ws = (u16*)d_ws;
    int* flag       = (int*)d_ws;
    u16* qkv_text   = ws + 64;
    u16* qkv_patch  = ws + 12582976;
    u16* attn_text  = ws + 62914624;
    u16* attn_patch = ws + 67108928;
    u16* cls_q      = ws + 83886144;
    u16* attn_cls   = ws + 83951680;
    u16* ctx      = qkv_text;
    u16* kv_int   = qkv_patch;
    u16* q_int    = qkv_patch + 8519680;
    u16* attn_int = qkv_patch + 8523776;
    u16* out_ws   = qkv_patch + 8527872;
    u16* to_ws = out_ws;
    u16* po_ws = out_ws + 4194304;
    u16* co_ws = out_ws + 20971520;
    u16* io_ws = out_ws + 21037056;

    hipFuncSetAttribute((const void*)gemm_ares,
                        hipFuncAttributeMaxDynamicSharedMemorySize, GEMM_LDS_BYTES);

    dim3 blk(256);
    const int SH = GEMM_LDS_BYTES;
    detect_dtype<<<1, blk, 0, stream>>>((const u16*)text, flag);
    // QKV projections
    gemm_ares<<<dim3(64, 4),  blk, SH, stream>>>(text,  t_win, t_bin, qkv_text, 4096, 3072, 12, 0, 0, 1, flag);
    gemm_ares<<<dim3(256, 1), blk, SH, stream>>>(patch, p_win, p_bin, qkv_patch, 16384, 3072, 48, 0, 0, 1, flag);
    gemm_ares<<<dim3(1, 16),  blk, SH, stream>>>(cls,   p_win, p_bin, cls_q, 64, 1024, 1, 0, 0, 1, flag);
    // attention (MFMA flash)
    attn_flash<<<dim3(16, 16, 4), blk, 0, stream>>>(qkv_text, attn_text, 1024, 1);
    attn_flash<<<dim3(4, 16, 64), blk, 0, stream>>>(qkv_patch, attn_patch, 256, 0);
    attn_cross<<<dim3(16, 64), dim3(64), 0, stream>>>(qkv_patch, cls_q, attn_cls, 0);
    // output projections
    gemm_ares<<<dim3(64, 4),  blk, SH, stream>>>(attn_text,  t_wout, t_bout, to_ws, 4096, 1024, 4, 0, 0, 0, flag);
    gemm_ares<<<dim3(256, 1), blk, SH, stream>>>(attn_patch, p_wout, p_bout, po_ws, 16384, 1024, 16, 0, 0, 0, flag);
    gemm_ares<<<dim3(1, 16),  blk, SH, stream>>>(attn_cls,   p_wout, p_bout, co_ws, 64, 1024, 1, 0, 0, 0, flag);
    // INT path
    build_ctx<<<dim3(2080), blk, 0, stream>>>(to_ws, co_ws, ctx);
    gemm_ares<<<dim3(65, 4), blk, SH, stream>>>(ctx, i_win, i_bin, kv_int, 4160, 2048, 8, 1024, 1024, 0, flag);
    gemm_ares<<<dim3(1, 16), blk, SH, stream>>>(intok, i_win, i_bin, q_int, 4, 1024, 1, 0, 0, 1, flag);
    attn_cross<<<dim3(16, 4), dim3(64), 0, stream>>>(kv_int, q_int, attn_int, 1);
    gemm_ares<<<dim3(1, 16), blk, SH, stream>>>(attn_int, i_wout, i_bout, io_ws, 4, 1024, 1, 0, 0, 0, flag);
    // emit
    emit_out<<<dim3(10274), blk, 0, stream>>>(out_ws, d_out, 2630144, flag);
}